// Round 1
// baseline (1564.027 us; speedup 1.0000x reference)
//
#include <hip/hip_runtime.h>
#include <hip/hip_bf16.h>

#define S 64
#define CIN 16
#define COUT 16
#define BATCH 4

// Direct 3x3x3 conv, padding=1, stride=1. Block = 256 threads handles a
// 64(x) x 16(y) x 1(z) output tile for one (b, cout). Each thread computes
// 4 consecutive x-outputs. Weights for this cout staged in LDS (432 floats,
// broadcast reads). Input loads hit L1/L2 heavily (3-plane window per cin).
__global__ __launch_bounds__(256) void conv3d_direct(
    const float* __restrict__ x,
    const float* __restrict__ w,
    const float* __restrict__ bias,
    float* __restrict__ out)
{
    __shared__ float wsh[CIN * 27];

    const int bz   = blockIdx.z;       // b*COUT + cout
    const int b    = bz >> 4;
    const int cout = bz & 15;
    const int z    = blockIdx.y;       // 0..63
    const int yt   = blockIdx.x;       // 0..3 -> y in [yt*16, yt*16+16)

    // stage this cout's weights: CIN*27 = 432 floats
    for (int i = threadIdx.x; i < CIN * 27; i += 256)
        wsh[i] = w[cout * (CIN * 27) + i];
    __syncthreads();

    const int tx = threadIdx.x & 15;   // x-group: covers x0..x0+3
    const int ty = threadIdx.x >> 4;   // 0..15
    const int y  = yt * 16 + ty;
    const int x0 = tx * 4;

    float acc0 = bias[cout];
    float acc1 = acc0, acc2 = acc0, acc3 = acc0;

    const float* xb = x + (size_t)b * CIN * (S * S * S);

    for (int cin = 0; cin < CIN; ++cin) {
        const float* xc = xb + cin * (S * S * S);
        const float* wc = wsh + cin * 27;
        #pragma unroll
        for (int kd = 0; kd < 3; ++kd) {
            const int zz = z + kd - 1;
            if (zz < 0 || zz >= S) continue;
            #pragma unroll
            for (int kh = 0; kh < 3; ++kh) {
                const int yy = y + kh - 1;
                if (yy < 0 || yy >= S) continue;
                const float* xr = xc + ((size_t)zz * S + yy) * S;
                // need columns x0-1 .. x0+4 ; middle 4 are 16B-aligned
                const float4 vm = *reinterpret_cast<const float4*>(xr + x0);
                const float v0 = (x0 > 0)     ? xr[x0 - 1] : 0.0f;
                const float v5 = (x0 + 4 < S) ? xr[x0 + 4] : 0.0f;
                const float* wk = wc + (kd * 3 + kh) * 3;
                const float w0 = wk[0], w1 = wk[1], w2 = wk[2];
                acc0 = fmaf(v0,   w0, fmaf(vm.x, w1, fmaf(vm.y, w2, acc0)));
                acc1 = fmaf(vm.x, w0, fmaf(vm.y, w1, fmaf(vm.z, w2, acc1)));
                acc2 = fmaf(vm.y, w0, fmaf(vm.z, w1, fmaf(vm.w, w2, acc2)));
                acc3 = fmaf(vm.z, w0, fmaf(vm.w, w1, fmaf(v5,   w2, acc3)));
            }
        }
    }

    const size_t oidx = (((size_t)(b * COUT + cout) * S + z) * S + y) * S + x0;
    *reinterpret_cast<float4*>(out + oidx) = make_float4(acc0, acc1, acc2, acc3);
}

extern "C" void kernel_launch(void* const* d_in, const int* in_sizes, int n_in,
                              void* d_out, int out_size, void* d_ws, size_t ws_size,
                              hipStream_t stream)
{
    (void)in_sizes; (void)n_in; (void)out_size; (void)d_ws; (void)ws_size;
    const float* x    = (const float*)d_in[0];
    const float* w    = (const float*)d_in[1];
    const float* bias = (const float*)d_in[2];
    float* out        = (float*)d_out;

    dim3 grid(S / 16, S, BATCH * COUT);   // (ytiles, z, b*cout) = (4, 64, 64)
    conv3d_direct<<<grid, 256, 0, stream>>>(x, w, bias, out);
}

// Round 2
// 187.342 us; speedup vs baseline: 8.3485x; 8.3485x over previous
//
#include <hip/hip_runtime.h>
#include <hip/hip_bf16.h>

#define S 64
#define CINV 16
#define COUTV 16
#define BATCH 4
#define SH 66                                  // S + 2 halo
#define XT_B ((size_t)SH * SH * SH * 32)       // bytes per batch: 9,199,872
#define XT_TOTAL (XT_B * BATCH)                // 36,799,488 B
#define NPAIR 14

typedef short bf16x8 __attribute__((ext_vector_type(8)));
typedef float f32x4 __attribute__((ext_vector_type(4)));

// Pack weights into MFMA B-fragment layout: wf[p][lane][j] = B[k=8*(lane>>4)+j][cout=lane&15]
// for tap pair p (taps 2p, 2p+1; k<16 -> even tap, k>=16 -> odd tap; tap 27 = zero pad).
__global__ __launch_bounds__(256) void prep_wf(const float* __restrict__ w,
                                               ushort* __restrict__ wf) {
    for (int e = threadIdx.x; e < NPAIR * 64 * 8; e += 256) {
        int p = e >> 9, l = (e >> 3) & 63, j = e & 7;
        int k = ((l >> 4) << 3) + j;
        int tap = 2 * p + (k >> 4);
        int cin = k & 15, cout = l & 15;
        float v = (tap < 27) ? w[(cout * 16 + cin) * 27 + tap] : 0.0f;
        __hip_bfloat16 hb = __float2bfloat16(v);
        wf[e] = *reinterpret_cast<ushort*>(&hb);
    }
}

// NCDHW fp32 -> channel-last bf16 with zero halo: xt[b][z+1][y+1][x+1][cin].
// One block per (z, b); LDS transpose so both global read and write are coalesced.
__global__ __launch_bounds__(256) void xform(const float* __restrict__ x,
                                             ushort* __restrict__ xt) {
    __shared__ ushort tl[4][64][18];           // +2 pad: conflict-free b16 writes
    const int z = blockIdx.x, b = blockIdx.y;
    const int t = threadIdx.x;
    const int r = t >> 6, xx = t & 63;
    ushort* xtb = xt + (size_t)b * (XT_B / 2);
    for (int yq = 0; yq < 16; ++yq) {
        __syncthreads();                       // protect tl from previous readers
        for (int cin = 0; cin < 16; ++cin) {
            float v = x[(((size_t)(b * 16 + cin) * 64 + z) * 64 + yq * 4 + r) * 64 + xx];
            __hip_bfloat16 hb = __float2bfloat16(v);
            tl[r][xx][cin] = *reinterpret_cast<ushort*>(&hb);
        }
        __syncthreads();
        #pragma unroll
        for (int rr = 0; rr < 4; ++rr) {       // each row: 2048 contiguous bytes
            int xs = t >> 2, cs = (t & 3) * 4;
            uint v0 = *reinterpret_cast<const uint*>(&tl[rr][xs][cs]);
            uint v1 = *reinterpret_cast<const uint*>(&tl[rr][xs][cs + 2]);
            size_t dst = ((size_t)(z + 1) * SH + (yq * 4 + rr + 1)) * SH * 16 + 16
                       + (size_t)t * 4;        // ushort offset
            uint* dp = reinterpret_cast<uint*>(xtb + dst);
            dp[0] = v0; dp[1] = v1;
        }
    }
}

// Implicit GEMM conv: 1 wave = 16 x-positions (M) x 16 couts (N), K=432 via 14
// MFMA 16x16x32 (tap pairs). A-frag slot k = 8*(lane>>4)+j matches wf's k map,
// so result is invariant to the exact HW k-permutation.
__global__ __launch_bounds__(256) void conv_mfma(const ushort* __restrict__ xt,
                                                 const ushort* __restrict__ wf,
                                                 const float* __restrict__ bias,
                                                 float* __restrict__ out) {
    const int t = threadIdx.x;
    const int lane = t & 63, wave = t >> 6;
    const int hi = lane >> 4, lo = lane & 15;
    const int y = blockIdx.x, z = blockIdx.y, b = blockIdx.z;

    bf16x8 bfr[NPAIR];
    #pragma unroll
    for (int p = 0; p < NPAIR; ++p)
        bfr[p] = *reinterpret_cast<const bf16x8*>(wf + ((size_t)p * 64 + lane) * 8);

    const char* xtb = reinterpret_cast<const char*>(xt) + (size_t)b * XT_B;
    const size_t base = ((size_t)(z * SH + y) * SH + wave * 16 + lo) * 32 + (hi & 1) * 16;

    const float bv = bias[lo];
    f32x4 acc = {bv, bv, bv, bv};

    #pragma unroll
    for (int p = 0; p < NPAIR; ++p) {
        const int t0 = 2 * p, t1 = 2 * p + 1;
        const int o0 = (((t0 / 9) * SH + (t0 % 9) / 3) * SH + (t0 % 3)) * 32;
        const int o1 = (t1 < 27) ? (((t1 / 9) * SH + (t1 % 9) / 3) * SH + (t1 % 3)) * 32 : 0;
        const char* pa;
        if (hi < 2)        pa = xtb + base + o0;
        else if (t1 < 27)  pa = xtb + base + o1;
        else               pa = xtb + lane * 16;   // z=-1 halo plane: all zeros
        bf16x8 af = *reinterpret_cast<const bf16x8*>(pa);
        acc = __builtin_amdgcn_mfma_f32_16x16x32_bf16(af, bfr[p], acc, 0, 0, 0);
    }

    // Epilogue: redistribute through LDS so stores are 256B-contiguous per cout row.
    __shared__ float osh[64][17];
    #pragma unroll
    for (int j = 0; j < 4; ++j)
        osh[wave * 16 + hi * 4 + j][lo] = acc[j];   // row=(hi*4+j)=x, col=lo=cout
    __syncthreads();
    const int cout = t >> 4, xs = (t & 15) * 4;
    float4 o = make_float4(osh[xs][cout], osh[xs + 1][cout],
                           osh[xs + 2][cout], osh[xs + 3][cout]);
    *reinterpret_cast<float4*>(
        out + ((((size_t)b * 16 + cout) * 64 + z) * 64 + y) * 64 + xs) = o;
}

extern "C" void kernel_launch(void* const* d_in, const int* in_sizes, int n_in,
                              void* d_out, int out_size, void* d_ws, size_t ws_size,
                              hipStream_t stream)
{
    (void)in_sizes; (void)n_in; (void)out_size; (void)ws_size;
    const float* x    = (const float*)d_in[0];
    const float* w    = (const float*)d_in[1];
    const float* bias = (const float*)d_in[2];
    float* out        = (float*)d_out;

    ushort* xt = (ushort*)d_ws;
    ushort* wf = (ushort*)((char*)d_ws + XT_TOTAL);

    hipMemsetAsync(d_ws, 0, XT_TOTAL, stream);          // zero halo (and interior)
    prep_wf<<<1, 256, 0, stream>>>(w, wf);
    xform<<<dim3(64, BATCH), 256, 0, stream>>>(x, xt);
    conv_mfma<<<dim3(64, 64, BATCH), 256, 0, stream>>>(xt, wf, bias, out);
}

// Round 3
// 158.813 us; speedup vs baseline: 9.8482x; 1.1796x over previous
//
#include <hip/hip_runtime.h>
#include <hip/hip_bf16.h>

#define S 64
#define BATCH 4
#define SH 66                                   // S + 2 halo
#define PLANE_USH (SH * SH * 16)                // ushorts per z-plane: 69,696
#define XT_USH ((size_t)SH * PLANE_USH)         // ushorts per batch
#define XT_B (XT_USH * 2)                       // bytes per batch: 9,199,872
#define XT_TOTAL (XT_B * BATCH)
#define NPAIR 14

typedef short bf16x8 __attribute__((ext_vector_type(8)));
typedef float f32x4 __attribute__((ext_vector_type(4)));

// Pack weights into MFMA B-fragment layout: wf[p][lane][j] = B[k][cout=lane&15],
// k = 8*(lane>>4)+j; k<16 -> tap 2p, k>=16 -> tap 2p+1 (tap 27 = zero pad).
__global__ __launch_bounds__(256) void prep_wf(const float* __restrict__ w,
                                               ushort* __restrict__ wf) {
    for (int e = threadIdx.x; e < NPAIR * 64 * 8; e += 256) {
        int p = e >> 9, l = (e >> 3) & 63, j = e & 7;
        int k = ((l >> 4) << 3) + j;
        int tap = 2 * p + (k >> 4);
        int cin = k & 15, cout = l & 15;
        float v = (tap < 27) ? w[(cout * 16 + cin) * 27 + tap] : 0.0f;
        __hip_bfloat16 hb = __float2bfloat16(v);
        wf[e] = *reinterpret_cast<ushort*>(&hb);
    }
}

// NCDHW fp32 -> channel-last bf16 xt[b][z+1][y+1][x+1][cin], halo written as
// zeros by this kernel (no global memset). Grid (66, 4, B): z-plane, y-seg, b.
__global__ __launch_bounds__(256) void xform(const float* __restrict__ x,
                                             ushort* __restrict__ xt) {
    __shared__ ushort tl[4][64][18];            // stride 18 ush = 9 dwords: conflict-free
    const int zp = blockIdx.x;                  // xt z index 0..65
    const int yseg = blockIdx.y;                // 0..3 -> y rows [yseg*16, +16)
    const int b = blockIdx.z;
    const int t = threadIdx.x;
    ushort* xtb = xt + (size_t)b * XT_USH;
    ushort* plane = xtb + (size_t)zp * PLANE_USH;

    if (zp == 0 || zp == SH - 1) {              // z halo plane: all zeros
        uint4* p4 = reinterpret_cast<uint4*>(plane);   // 8712 uint4 per plane
        for (int i = yseg * 2178 + t; i < (yseg + 1) * 2178; i += 256)
            p4[i] = uint4{0, 0, 0, 0};
        return;
    }
    const int z = zp - 1;
    if (yseg == 0) {                            // y'=0 halo row (2112 B)
        uint4* p4 = reinterpret_cast<uint4*>(plane);
        if (t < 132) p4[t] = uint4{0, 0, 0, 0};
    } else if (yseg == 3) {                     // y'=65 halo row
        uint4* p4 = reinterpret_cast<uint4*>(plane + 65 * SH * 16);
        if (t < 132) p4[t] = uint4{0, 0, 0, 0};
    }

    const int r = t >> 6, xx = t & 63;
    for (int yq = 0; yq < 4; ++yq) {
        const int y = yseg * 16 + yq * 4;       // + r for the read row
        __syncthreads();
        #pragma unroll
        for (int cin = 0; cin < 16; ++cin) {
            float v = x[(((size_t)(b * 16 + cin) * S + z) * S + (y + r)) * S + xx];
            __hip_bfloat16 hb = __float2bfloat16(v);
            tl[r][xx][cin] = *reinterpret_cast<ushort*>(&hb);
        }
        __syncthreads();
        #pragma unroll
        for (int rr = 0; rr < 4; ++rr) {        // row y+rr: 2048B interior, contiguous
            ushort* row = plane + (size_t)(y + rr + 1) * (SH * 16);
            const int xs = t >> 2, cs = (t & 3) * 4;
            uint v0 = *reinterpret_cast<const uint*>(&tl[rr][xs][cs]);
            uint v1 = *reinterpret_cast<const uint*>(&tl[rr][xs][cs + 2]);
            uint* dp = reinterpret_cast<uint*>(row + 16 + t * 4);
            dp[0] = v0; dp[1] = v1;
            if (t == 0) {                       // x'=0 halo (32 B)
                uint4* h = reinterpret_cast<uint4*>(row);
                h[0] = uint4{0, 0, 0, 0}; h[1] = uint4{0, 0, 0, 0};
            } else if (t == 1) {                // x'=65 halo (32 B)
                uint4* h = reinterpret_cast<uint4*>(row + 65 * 16);
                h[0] = uint4{0, 0, 0, 0}; h[1] = uint4{0, 0, 0, 0};
            }
        }
    }
}

// Implicit GEMM conv: wave = 64 x (M, 4 accs) x 16 couts (N), K=432 via 14 tap
// pairs; 56 MFMAs/wave over 4 independent acc chains; B-frags loaded once.
__global__ __launch_bounds__(256) void conv_mfma(const ushort* __restrict__ xt,
                                                 const ushort* __restrict__ wf,
                                                 const float* __restrict__ bias,
                                                 float* __restrict__ out) {
    const int t = threadIdx.x;
    const int lane = t & 63, w = t >> 6;
    const int hi = lane >> 4, lo = lane & 15;
    const int y = blockIdx.x * 4 + w, z = blockIdx.y, b = blockIdx.z;

    bf16x8 bfr[NPAIR];
    #pragma unroll
    for (int p = 0; p < NPAIR; ++p)
        bfr[p] = *reinterpret_cast<const bf16x8*>(wf + ((size_t)p * 64 + lane) * 8);

    const char* xtb = reinterpret_cast<const char*>(xt) + (size_t)b * XT_B;
    const char* zerop = xtb + lane * 16;        // inside z'=0 plane: zeros
    const char* base0 = xtb + ((size_t)(z * SH + y) * SH + lo) * 32 + (hi & 1) * 16;

    const float bv = bias[lo];
    f32x4 acc[4];
    #pragma unroll
    for (int g = 0; g < 4; ++g) acc[g] = {bv, bv, bv, bv};

    #pragma unroll
    for (int p = 0; p < NPAIR; ++p) {
        const int t0 = 2 * p, t1 = 2 * p + 1;
        const int o0 = (((t0 / 9) * SH + (t0 % 9) / 3) * SH + (t0 % 3)) * 32;
        const int o1 = (t1 < 27) ? (((t1 / 9) * SH + (t1 % 9) / 3) * SH + (t1 % 3)) * 32 : 0;
        const int osel = (hi < 2) ? o0 : o1;
        const bool zsel = (hi >= 2) && (t1 >= 27);
        #pragma unroll
        for (int g = 0; g < 4; ++g) {
            const char* pa = zsel ? zerop : (base0 + g * (16 * 32) + osel);
            bf16x8 af = *reinterpret_cast<const bf16x8*>(pa);
            acc[g] = __builtin_amdgcn_mfma_f32_16x16x32_bf16(af, bfr[p], acc[g], 0, 0, 0);
        }
    }

    // Epilogue through LDS: per cout row, 256B-contiguous float4 stores.
    __shared__ float osh[4][64][17];
    #pragma unroll
    for (int g = 0; g < 4; ++g)
        #pragma unroll
        for (int j = 0; j < 4; ++j)
            osh[w][g * 16 + hi * 4 + j][lo] = acc[g][j];
    __syncthreads();
    const int cout = t >> 4, xs = (t & 15) * 4;
    #pragma unroll
    for (int ww = 0; ww < 4; ++ww) {
        float4 o = make_float4(osh[ww][xs][cout], osh[ww][xs + 1][cout],
                               osh[ww][xs + 2][cout], osh[ww][xs + 3][cout]);
        *reinterpret_cast<float4*>(
            out + ((((size_t)b * 16 + cout) * S + z) * S + (blockIdx.x * 4 + ww)) * S + xs) = o;
    }
}

extern "C" void kernel_launch(void* const* d_in, const int* in_sizes, int n_in,
                              void* d_out, int out_size, void* d_ws, size_t ws_size,
                              hipStream_t stream)
{
    (void)in_sizes; (void)n_in; (void)out_size; (void)ws_size;
    const float* x    = (const float*)d_in[0];
    const float* w    = (const float*)d_in[1];
    const float* bias = (const float*)d_in[2];
    float* out        = (float*)d_out;

    ushort* xt = (ushort*)d_ws;
    ushort* wf = (ushort*)((char*)d_ws + XT_TOTAL);

    prep_wf<<<1, 256, 0, stream>>>(w, wf);
    xform<<<dim3(SH, 4, BATCH), 256, 0, stream>>>(x, xt);
    conv_mfma<<<dim3(16, S, BATCH), 256, 0, stream>>>(xt, wf, bias, out);
}

// Round 4
// 142.715 us; speedup vs baseline: 10.9591x; 1.1128x over previous
//
#include <hip/hip_runtime.h>
#include <hip/hip_bf16.h>

#define S 64
#define BATCH 4
#define SH 66                                   // S + 2 halo
#define ROW_B 2112                              // bytes per (z,y) row: 66 x * 16 cin * 2
#define PLANE_B ((size_t)SH * ROW_B)            // 139,392 B per z-plane
#define XT_B ((size_t)SH * PLANE_B)             // bytes per batch
#define XT_TOTAL (XT_B * BATCH)
#define NPAIR 14
#define SLAB_P 12672                            // staged plane chunk: 6 rows * 2112

typedef short bf16x8 __attribute__((ext_vector_type(8)));
typedef float f32x4 __attribute__((ext_vector_type(4)));

// Pack weights into MFMA B-fragment layout: wf[p][lane][j] = B[k][cout=lane&15],
// k = 8*(lane>>4)+j; k<16 -> tap 2p, k>=16 -> tap 2p+1 (tap 27 = zero pad).
__global__ __launch_bounds__(256) void prep_wf(const float* __restrict__ w,
                                               ushort* __restrict__ wf) {
    int e = blockIdx.x * 256 + threadIdx.x;     // 28 blocks * 256 = 7168 exact
    int p = e >> 9, l = (e >> 3) & 63, j = e & 7;
    int k = ((l >> 4) << 3) + j;
    int tap = 2 * p + (k >> 4);
    int cin = k & 15, cout = l & 15;
    float v = (tap < 27) ? w[(cout * 16 + cin) * 27 + tap] : 0.0f;
    __hip_bfloat16 hb = __float2bfloat16(v);
    wf[e] = *reinterpret_cast<ushort*>(&hb);
}

// NCDHW fp32 -> channel-last bf16 xt[b][z+1][y+1][x+1][cin]; halos written as
// zeros here (no global memset). Grid (66, 16, B). One barrier pair per block.
__global__ __launch_bounds__(256) void xform(const float* __restrict__ x,
                                             char* __restrict__ xt) {
    __shared__ ushort tl[4][64][18];            // x-stride 36B (9 dw, odd): spread banks
    const int zp = blockIdx.x, yq = blockIdx.y, b = blockIdx.z;
    const int t = threadIdx.x;
    char* xtb = xt + (size_t)b * XT_B;
    char* plane = xtb + (size_t)zp * PLANE_B;

    if (zp == 0 || zp == SH - 1) {              // z halo plane: zero-fill, strided
        uint4* p4 = reinterpret_cast<uint4*>(plane);
        for (int i = yq * 256 + t; i < (int)(PLANE_B / 16); i += 4096)
            p4[i] = uint4{0, 0, 0, 0};
        return;
    }
    const int z = zp - 1;
    const int y0 = yq * 4;                      // input rows y0..y0+3
    const int cin = t >> 4, xq = t & 15;

    // load 4 rows as float4, convert, transpose through LDS
    float4 v[4];
    #pragma unroll
    for (int i = 0; i < 4; ++i)
        v[i] = *reinterpret_cast<const float4*>(
            x + (((size_t)(b * 16 + cin) * S + z) * S + (y0 + i)) * S + xq * 4);
    #pragma unroll
    for (int i = 0; i < 4; ++i) {
        #pragma unroll
        for (int u = 0; u < 4; ++u) {
            float f = (u == 0) ? v[i].x : (u == 1) ? v[i].y : (u == 2) ? v[i].z : v[i].w;
            __hip_bfloat16 hb = __float2bfloat16(f);
            tl[i][xq * 4 + u][cin] = *reinterpret_cast<ushort*>(&hb);
        }
    }
    __syncthreads();

    // write out: 4 interior rows, 2048B contiguous each; plus halos
    const int xx = t >> 2, c4 = (t & 3) * 4;
    #pragma unroll
    for (int i = 0; i < 4; ++i) {
        char* row = plane + (size_t)(y0 + i + 1) * ROW_B;
        uint a = *reinterpret_cast<const uint*>(&tl[i][xx][c4]);
        uint bq = *reinterpret_cast<const uint*>(&tl[i][xx][c4 + 2]);
        uint2 val = {a, bq};
        *reinterpret_cast<uint2*>(row + 32 + t * 8) = val;
        if (t == 0) {                           // x'=0 halo (32B)
            uint4 zz4 = {0, 0, 0, 0};
            reinterpret_cast<uint4*>(row)[0] = zz4;
            reinterpret_cast<uint4*>(row)[1] = zz4;
        } else if (t == 1) {                    // x'=65 halo (32B)
            uint4 zz4 = {0, 0, 0, 0};
            reinterpret_cast<uint4*>(row + 65 * 32)[0] = zz4;
            reinterpret_cast<uint4*>(row + 65 * 32)[1] = zz4;
        }
    }
    if (yq == 0) {                              // y'=0 halo row
        uint4* p4 = reinterpret_cast<uint4*>(plane);
        if (t < 132) p4[t] = uint4{0, 0, 0, 0};
    } else if (yq == 15) {                      // y'=65 halo row
        uint4* p4 = reinterpret_cast<uint4*>(plane + 65 * ROW_B);
        if (t < 132) p4[t] = uint4{0, 0, 0, 0};
    }
}

// Implicit GEMM conv, LDS-staged A. Block = 4 waves at one z, 4 consecutive y.
// Stage 3 z-planes x 6 y-rows (38,016B) linearly into LDS, then each wave does
// 56 ds_read_b128 + 56 MFMA (4 x-groups x 14 tap pairs). Pad tap's B-column is
// zero, so its A half may be garbage. Epilogue reuses the slab.
__global__ __launch_bounds__(256) void conv_mfma(const char* __restrict__ xt,
                                                 const ushort* __restrict__ wf,
                                                 const float* __restrict__ bias,
                                                 float* __restrict__ out) {
    __shared__ char slab[3 * SLAB_P];           // 38,016 B
    const int t = threadIdx.x, lane = t & 63, wid = t >> 6;
    const int hi = lane >> 4, lo = lane & 15;
    const int y0 = blockIdx.x * 4, z0 = blockIdx.y, b = blockIdx.z;
    const char* xtb = xt + (size_t)b * XT_B;

    // B fragments (global, L1-hot, 14 x 1KB coalesced)
    bf16x8 bfr[NPAIR];
    #pragma unroll
    for (int p = 0; p < NPAIR; ++p)
        bfr[p] = *reinterpret_cast<const bf16x8*>(wf + ((size_t)p * 64 + lane) * 8);

    // stage slab: 3 planes x 6 rows, 792 lane-16B ops per plane
    #pragma unroll
    for (int p = 0; p < 3; ++p) {
        const char* gsrc = xtb + ((size_t)(z0 + p) * SH + y0) * ROW_B;
        #pragma unroll
        for (int i = 0; i < 4; ++i) {
            int idx = i * 256 + t;
            if (idx < SLAB_P / 16) {
                uint4 val = *reinterpret_cast<const uint4*>(gsrc + idx * 16);
                *reinterpret_cast<uint4*>(slab + p * SLAB_P + idx * 16) = val;
            }
        }
    }

    const float bv = bias[lo];
    f32x4 acc[4];
    #pragma unroll
    for (int g = 0; g < 4; ++g) acc[g] = {bv, bv, bv, bv};

    __syncthreads();

    #pragma unroll
    for (int p = 0; p < NPAIR; ++p) {
        const int t0 = 2 * p;
        const int t1 = (2 * p + 1 < 27) ? 2 * p + 1 : 26;   // pad pair: B=0, A irrelevant
        const int o0 = (t0 / 9) * SLAB_P + ((t0 / 3) % 3 + wid) * ROW_B + (lo + t0 % 3) * 32;
        const int o1 = (t1 / 9) * SLAB_P + ((t1 / 3) % 3 + wid) * ROW_B + (lo + t1 % 3) * 32;
        const int sel = ((hi < 2) ? o0 : o1) + ((hi & 1) << 4);
        #pragma unroll
        for (int g = 0; g < 4; ++g) {
            bf16x8 af = *reinterpret_cast<const bf16x8*>(slab + sel + g * 512);
            acc[g] = __builtin_amdgcn_mfma_f32_16x16x32_bf16(af, bfr[p], acc[g], 0, 0, 0);
        }
    }

    __syncthreads();                            // slab reads done; reuse as epilogue buf
    float (*osh)[64][17] = reinterpret_cast<float (*)[64][17]>(slab);
    #pragma unroll
    for (int g = 0; g < 4; ++g)
        #pragma unroll
        for (int j = 0; j < 4; ++j)
            osh[wid][g * 16 + hi * 4 + j][lo] = acc[g][j];   // row=x, col=cout
    __syncthreads();
    const int cout = t >> 4, xs = (t & 15) * 4;
    #pragma unroll
    for (int ww = 0; ww < 4; ++ww) {
        float4 o = make_float4(osh[ww][xs][cout], osh[ww][xs + 1][cout],
                               osh[ww][xs + 2][cout], osh[ww][xs + 3][cout]);
        *reinterpret_cast<float4*>(
            out + ((((size_t)b * 16 + cout) * S + z0) * S + (y0 + ww)) * S + xs) = o;
    }
}

extern "C" void kernel_launch(void* const* d_in, const int* in_sizes, int n_in,
                              void* d_out, int out_size, void* d_ws, size_t ws_size,
                              hipStream_t stream)
{
    (void)in_sizes; (void)n_in; (void)out_size; (void)ws_size;
    const float* x    = (const float*)d_in[0];
    const float* w    = (const float*)d_in[1];
    const float* bias = (const float*)d_in[2];
    float* out        = (float*)d_out;

    char* xt   = (char*)d_ws;
    ushort* wf = (ushort*)((char*)d_ws + XT_TOTAL);

    prep_wf<<<28, 256, 0, stream>>>(w, wf);
    xform<<<dim3(SH, 16, BATCH), 256, 0, stream>>>(x, xt);
    conv_mfma<<<dim3(16, S, BATCH), 256, 0, stream>>>(xt, wf, bias, out);
}